// Round 4
// baseline (428.836 us; speedup 1.0000x reference)
//
#include <hip/hip_runtime.h>
#include <cstdint>

typedef unsigned short ushort_t;
typedef unsigned int uint_t;
typedef _Float16 f16x8 __attribute__((ext_vector_type(8)));
typedef float f32x4 __attribute__((ext_vector_type(4)));

#define N_ROWS 32768
#define DK 512
#define NC_MAIN 1024
#define NCB 1792  // 1024 + 512 + 256
#define NTILE 14  // 1792 / 128
#define NBLK_RG 8192  // rescue_gather blocks (4 rows each)

// d_out layout (floats, concatenated reference outputs)
#define MAIN_OFF 0
#define SUB_OFF  16777216
#define LOSS_OFF 33554432
#define MSK_OFF  33554433
#define UNIQ_OFF 33562625

__device__ __forceinline__ uint_t umin_(uint_t a, uint_t b) { return a < b ? a : b; }
__device__ __forceinline__ uint_t umax_(uint_t a, uint_t b) { return a > b ? a : b; }

// ---------------------------------------------------------------------------
// Build combined codebook CB[1792][512] (fp32) AND its f16 copy cbh.
__global__ __launch_bounds__(256) void build_subcb(
    const float* __restrict__ c, const float* __restrict__ W1,
    const float* __restrict__ b1, const float* __restrict__ W2,
    const float* __restrict__ b2, float* __restrict__ CB,
    _Float16* __restrict__ cbh)
{
    int tid = threadIdx.x;
    int tx = tid & 63, ty = tid >> 6;
    int col = blockIdx.x * 64 + tx;
    int row0 = blockIdx.y * 16 + ty * 4;
    if (row0 < 1024) {
#pragma unroll
        for (int r = 0; r < 4; ++r) {
            float v = c[(row0 + r) * DK + col];
            CB[(row0 + r) * DK + col] = v;
            cbh[(row0 + r) * DK + col] = (_Float16)v;
        }
    } else {
        int i0 = row0 - 1024;
        const float* W;
        const float* b;
        if (i0 < 512) { W = W1; b = b1; }
        else          { W = W2; b = b2; i0 -= 512; }
        float acc[4] = {0.f, 0.f, 0.f, 0.f};
#pragma unroll 8
        for (int j = 0; j < 1024; ++j) {
            float cv = c[j * DK + col];
#pragma unroll
            for (int r = 0; r < 4; ++r)
                acc[r] += W[(i0 + r) * 1024 + j] * cv;
        }
#pragma unroll
        for (int r = 0; r < 4; ++r) {
            float v = acc[r] + b[i0 + r];
            CB[(row0 + r) * DK + col] = v;
            cbh[(row0 + r) * DK + col] = (_Float16)v;
        }
    }
}

// ---------------------------------------------------------------------------
__global__ __launch_bounds__(64) void row_norms(const float* __restrict__ CB,
                                                float* __restrict__ norms) {
    int row = blockIdx.x;
    int lane = threadIdx.x;
    const float4* p = (const float4*)(CB + (size_t)row * DK);
    float s = 0.f;
#pragma unroll
    for (int i = lane; i < 128; i += 64) {
        float4 v = p[i];
        s += v.x * v.x + v.y * v.y + v.z * v.z + v.w * v.w;
    }
#pragma unroll
    for (int off = 32; off; off >>= 1) s += __shfl_down(s, off, 64);
    if (lane == 0) norms[row] = s;
}

// ---------------------------------------------------------------------------
// fp32 -> f16 (RN) for x, 8 elems/thread; also zeroes `used` (init fused).
__global__ __launch_bounds__(256) void cvt_x(const float* __restrict__ in,
                                             _Float16* __restrict__ out,
                                             int* __restrict__ used) {
    int i = blockIdx.x * 256 + threadIdx.x;
    if (i < 1024) used[i] = 0;
    const float4* p = (const float4*)in + (size_t)i * 2;
    float4 a = p[0], b = p[1];
    f16x8 o;
    o[0] = (_Float16)a.x; o[1] = (_Float16)a.y; o[2] = (_Float16)a.z; o[3] = (_Float16)a.w;
    o[4] = (_Float16)b.x; o[5] = (_Float16)b.y; o[6] = (_Float16)b.z; o[7] = (_Float16)b.w;
    *((f16x8*)out + i) = o;
}

// ---------------------------------------------------------------------------
__device__ __forceinline__ void async16(void* lds, const void* g) {
    __builtin_amdgcn_global_load_lds(
        (const __attribute__((address_space(1))) unsigned int*)(uintptr_t)g,
        (__attribute__((address_space(3))) unsigned int*)(uintptr_t)lds,
        16, 0, 0);
}

// ---------------------------------------------------------------------------
// MFMA f16 GEMM S = xh . cbh^T — ONE WAVE per block, 128x128 output tile,
// BK=32, zero barriers.
// Rationale (rounds 0-3 post-mortem): all multi-wave schedules pinned at
// ~94 µs because per-wave 64/128-col tiles give 0.023-0.031 LDS-read B/FLOP
// -> LDS pipe time ~ MFMA time, and barrier lockstep serializes the pipes.
// 128x128 per-wave tile: 0.0156 B/FLOP -> 16 ds_read_b128 (~190 cyc) per
// 64-MFMA K-step (~1240 cyc/SIMD). Single-wave workgroup has NO barriers:
// global_load_lds + counted vmcnt (depth-1 prefetch, hides ~900 cyc HBM
// under the K-step) + compiler-counted lgkmcnt do all the sync.
// acc 8x8 f32x4 = 256 VGPR -> 1 wave/SIMD, 4 blocks/CU, LDS 4x32KB=128KB.
// Swizzle: granule g ^= (row>>1)&3 (invariant across i and mr) applied to
// global source (linear LDS dest) and ds_read addr -> 2-way (free) banks.
__global__ __launch_bounds__(64, 1) void gemm_topk(
    const _Float16* __restrict__ xh, const _Float16* __restrict__ cbh,
    const float* __restrict__ norms, uint2* __restrict__ candbuf)
{
    __shared__ __align__(16) ushort_t As[2][128 * 32];  // 16 KiB
    __shared__ __align__(16) ushort_t Bs[2][128 * 32];  // 16 KiB

    const int lane = threadIdx.x;          // 0..63
    const int lane15 = lane & 15, q = lane >> 4;

    // XCD-aware remap: 3584 blocks = 8 xcd * 448 slots; same-xcd consecutive
    // slots share an A row-strip (14 tileN each) -> strip L2-resident.
    const int bid = blockIdx.x;
    const int xcd = bid & 7;
    const int slot = bid >> 3;             // 0..447
    const int tileN = slot % NTILE;        // 0..13
    const int rowT = (slot / NTILE) * 8 + xcd;  // 0..255
    const int rowBase = rowT * 128;
    const int c0 = tileN * 128;

    // staging: granule d = i*64 + lane; row = d>>2 = i*16 + (lane>>2),
    // g = lane&3; swizzled source chunk sg = g ^ ((row>>1)&3); (row>>1)&3
    // = (lane>>3)&3 is invariant across i. Linear LDS dest (d*16 bytes).
    const int srow = lane >> 2;
    const int sg = (lane & 3) ^ ((lane >> 3) & 3);
    const size_t aO = (size_t)(rowBase + srow) * DK + (size_t)(sg * 8);
    const size_t bO = (size_t)(c0 + srow) * DK + (size_t)(sg * 8);
    const int ldsg = lane * 8;             // f16 elems; + i*512

#define STG(BUF, KT) do { \
    _Pragma("unroll") \
    for (int i_ = 0; i_ < 8; ++i_) { \
        async16(&As[(BUF)][ldsg + i_ * 512], xh  + aO + (size_t)i_ * (16 * DK) + (KT) * 32); \
        async16(&Bs[(BUF)][ldsg + i_ * 512], cbh + bO + (size_t)i_ * (16 * DK) + (KT) * 32); \
    } } while (0)

    // ds_read per-lane offset (f16 units): row t*16+lane15, granule
    // q ^ ((lane15>>1)&3)  [row[2:1] == lane15[2:1], invariant across t]
    const int rbase = lane15 * 32 + ((q ^ ((lane15 >> 1) & 3)) * 8);

    f32x4 acc[8][8];
#pragma unroll
    for (int mr = 0; mr < 8; ++mr)
#pragma unroll
        for (int nc = 0; nc < 8; ++nc) acc[mr][nc] = (f32x4)0.f;

    STG(0, 0);
#pragma unroll
    for (int kt = 0; kt < 16; ++kt) {
        const int b = kt & 1;
        if (kt < 15) {
            STG(b ^ 1, kt + 1);
            asm volatile("s_waitcnt vmcnt(16)" ::: "memory");  // kt landed
        } else {
            asm volatile("s_waitcnt vmcnt(0)" ::: "memory");
        }
        __builtin_amdgcn_sched_barrier(0);
        f16x8 av[8], bv[8];
#pragma unroll
        for (int mr = 0; mr < 8; ++mr)
            av[mr] = *(const f16x8*)&As[b][mr * 512 + rbase];
#pragma unroll
        for (int nc = 0; nc < 8; ++nc)
            bv[nc] = *(const f16x8*)&Bs[b][nc * 512 + rbase];
#pragma unroll
        for (int mr = 0; mr < 8; ++mr)
#pragma unroll
            for (int nc = 0; nc < 8; ++nc)
                acc[mr][nc] = __builtin_amdgcn_mfma_f32_16x16x32_f16(
                    av[mr], bv[nc], acc[mr][nc], 0, 0, 0);
    }
#undef STG

    // ---- epilogue: per-row top-2 over the 128-col tile, all in-wave ------
    float nrm[8];
    uint_t colG[8];
#pragma unroll
    for (int nc = 0; nc < 8; ++nc) {
        colG[nc] = (uint_t)(c0 + nc * 16 + lane15);
        nrm[nc] = norms[colG[nc]];
    }

#pragma unroll
    for (int mr = 0; mr < 8; ++mr) {
#pragma unroll
        for (int r = 0; r < 4; ++r) {
            uint_t k1 = 0xFFFFFFFFu, k2 = 0xFFFFFFFFu;
#pragma unroll
            for (int nc = 0; nc < 8; ++nc) {
                float s = fmaf(-2.f, acc[mr][nc][r], nrm[nc]);
                uint_t bb = __float_as_uint(s);
                uint_t u = bb ^ ((uint_t)((int)bb >> 31) | 0x80000000u);
                uint_t k = (u & 0xFFFFF800u) | colG[nc];
                uint_t n1 = umin_(k1, k);
                k2 = umin_(k2, umax_(k1, k));
                k1 = n1;
            }
#pragma unroll
            for (int m = 1; m <= 8; m <<= 1) {
                uint_t o1 = __shfl_xor(k1, m, 64);
                uint_t o2 = __shfl_xor(k2, m, 64);
                uint_t n1 = umin_(k1, o1);
                uint_t n2 = umin_(umax_(k1, o1), umin_(k2, o2));
                k1 = n1; k2 = n2;
            }
            if (lane15 == 0) {
                int grow = rowBase + mr * 16 + q * 4 + r;
                candbuf[(size_t)grow * NTILE + tileN] = make_uint2(k1, k2);
            }
        }
    }
}

// ---------------------------------------------------------------------------
// Per x-row: merge tile candidate keys per segment (top-4, pure u32 min/max on
// wave-uniform values), rescore exactly in fp32, pick argmin (tie -> lowest
// idx), gather rows, write outputs, per-block loss partials, mark used.
__device__ __forceinline__ void push4u(uint_t v, uint_t* bs) {
#pragma unroll
    for (int j = 0; j < 4; ++j) {
        uint_t lo = umin_(v, bs[j]);
        uint_t hi = umax_(v, bs[j]);
        bs[j] = lo; v = hi;
    }
}

__global__ __launch_bounds__(256) void rescue_gather(
    const float* __restrict__ x, const float* __restrict__ CB,
    const float* __restrict__ norms, const uint2* __restrict__ candbuf,
    float* __restrict__ main_out, float* __restrict__ sub_out,
    float2* __restrict__ lossPart, int* __restrict__ used)
{
    const int lane = threadIdx.x & 63;
    const int wv = threadIdx.x >> 6;
    const int r = blockIdx.x * 4 + wv;

    const float4* xp = (const float4*)(x + (size_t)r * DK) + lane * 2;
    float4 xa = xp[0], xb = xp[1];

    const uint2* cbp = candbuf + (size_t)r * NTILE;

    int si[12];
    {
        uint_t bs[4];
#pragma unroll
        for (int j = 0; j < 4; ++j) bs[j] = 0xFFFFFFFFu;
#pragma unroll
        for (int t = 0; t < 8; ++t) {
            uint2 e = cbp[t];
            push4u(__builtin_amdgcn_readfirstlane(e.x), bs);
            push4u(__builtin_amdgcn_readfirstlane(e.y), bs);
        }
#pragma unroll
        for (int j = 0; j < 4; ++j) si[j] = (int)(bs[j] & 2047u);
#pragma unroll
        for (int j = 0; j < 4; ++j) bs[j] = 0xFFFFFFFFu;
#pragma unroll
        for (int t = 8; t < 12; ++t) {
            uint2 e = cbp[t];
            push4u(__builtin_amdgcn_readfirstlane(e.x), bs);
            push4u(__builtin_amdgcn_readfirstlane(e.y), bs);
        }
#pragma unroll
        for (int j = 0; j < 4; ++j) si[4 + j] = (int)(bs[j] & 2047u);
#pragma unroll
        for (int j = 0; j < 4; ++j) bs[j] = 0xFFFFFFFFu;
#pragma unroll
        for (int t = 12; t < 14; ++t) {
            uint2 e = cbp[t];
            push4u(__builtin_amdgcn_readfirstlane(e.x), bs);
            push4u(__builtin_amdgcn_readfirstlane(e.y), bs);
        }
#pragma unroll
        for (int j = 0; j < 4; ++j) si[8 + j] = (int)(bs[j] & 2047u);
    }

    float d[12];
#pragma unroll
    for (int k = 0; k < 12; ++k) {
        const float4* cp = (const float4*)(CB + (size_t)si[k] * DK) + lane * 2;
        float4 a = cp[0], b = cp[1];
        d[k] = xa.x * a.x + xa.y * a.y + xa.z * a.z + xa.w * a.w
             + xb.x * b.x + xb.y * b.y + xb.z * b.z + xb.w * b.w;
    }
#pragma unroll
    for (int off = 32; off; off >>= 1)
#pragma unroll
        for (int k = 0; k < 12; ++k) d[k] += __shfl_xor(d[k], off, 64);

    float sc[12];
#pragma unroll
    for (int k = 0; k < 12; ++k) sc[k] = norms[si[k]] - 2.f * d[k];

    int pick[3];
#pragma unroll
    for (int g = 0; g < 3; ++g) {
        float bv = sc[g * 4]; int bidx = si[g * 4];
#pragma unroll
        for (int k = 1; k < 4; ++k) {
            float v = sc[g * 4 + k]; int idx = si[g * 4 + k];
            if (v < bv || (v == bv && idx < bidx)) { bv = v; bidx = idx; }
        }
        pick[g] = bidx;
    }
    const int A = pick[0], B = pick[1], C = pick[2];

    const float4* pa = (const float4*)(CB + (size_t)A * DK) + lane * 2;
    const float4* pb = (const float4*)(CB + (size_t)B * DK) + lane * 2;
    const float4* pc = (const float4*)(CB + (size_t)C * DK) + lane * 2;
    float4* mo = (float4*)(main_out + (size_t)r * DK) + lane * 2;
    float4* so = (float4*)(sub_out + (size_t)r * DK) + lane * 2;
    float em = 0.f, es = 0.f;
#pragma unroll
    for (int i = 0; i < 2; ++i) {
        float4 xq = (i == 0) ? xa : xb;
        float4 cm = pa[i];
        float4 q1 = pb[i];
        float4 q2 = pc[i];
        float4 cs;
        cs.x = 0.5f * (q1.x + q2.x);
        cs.y = 0.5f * (q1.y + q2.y);
        cs.z = 0.5f * (q1.z + q2.z);
        cs.w = 0.5f * (q1.w + q2.w);
        mo[i] = cm;
        so[i] = cs;
        float t;
        t = cm.x - xq.x; em += t * t;
        t = cm.y - xq.y; em += t * t;
        t = cm.z - xq.z; em += t * t;
        t = cm.w - xq.w; em += t * t;
        t = cs.x - xq.x; es += t * t;
        t = cs.y - xq.y; es += t * t;
        t = cs.z - xq.z; es += t * t;
        t = cs.w - xq.w; es += t * t;
    }
#pragma unroll
    for (int off = 32; off; off >>= 1) {
        em += __shfl_down(em, off, 64);
        es += __shfl_down(es, off, 64);
    }
    __shared__ float sm[8];
    if (lane == 0) {
        sm[wv] = em; sm[4 + wv] = es;
        used[A] = 1;  // benign race: same value
    }
    __syncthreads();
    if (threadIdx.x == 0) {
        lossPart[blockIdx.x] = make_float2(sm[0] + sm[1] + sm[2] + sm[3],
                                           sm[4] + sm[5] + sm[6] + sm[7]);
    }
}

// ---------------------------------------------------------------------------
__global__ __launch_bounds__(256) void finalize_kernel(
    const int* __restrict__ used, const float2* __restrict__ lossPart,
    const int* __restrict__ training, float* __restrict__ out)
{
    int tid = threadIdx.x;
    int cnt = 0;
    for (int i = tid; i < 1024; i += 256) cnt += (used[i] != 0);
    float em = 0.f, es = 0.f;
    for (int i = tid; i < NBLK_RG; i += 256) {
        float2 p = lossPart[i];
        em += p.x; es += p.y;
    }
#pragma unroll
    for (int off = 32; off; off >>= 1) {
        cnt += __shfl_down(cnt, off, 64);
        em += __shfl_down(em, off, 64);
        es += __shfl_down(es, off, 64);
    }
    __shared__ int sc[4];
    __shared__ float se[4], ss[4];
    if ((tid & 63) == 0) { sc[tid >> 6] = cnt; se[tid >> 6] = em; ss[tid >> 6] = es; }
    __syncthreads();
    if (tid == 0) {
        int total = sc[0] + sc[1] + sc[2] + sc[3];
        float tl = 0.f;
        if (*training) {
            float l0 = se[0] + se[1] + se[2] + se[3];
            float l1 = ss[0] + ss[1] + ss[2] + ss[3];
            tl = 1.25f * (l0 + l1) * (1.0f / ((float)N_ROWS * (float)DK));
        }
        out[LOSS_OFF] = tl;
        out[UNIQ_OFF] = (float)total;
    }
    for (int i = tid; i < 8192; i += 256) out[MSK_OFF + i] = 0.f;
}

// ---------------------------------------------------------------------------
extern "C" void kernel_launch(void* const* d_in, const int* in_sizes, int n_in,
                              void* d_out, int out_size, void* d_ws, size_t ws_size,
                              hipStream_t stream) {
    const float* x = (const float*)d_in[0];
    const float* c = (const float*)d_in[1];
    const float* W1 = (const float*)d_in[2];
    const float* b1 = (const float*)d_in[3];
    const float* W2 = (const float*)d_in[4];
    const float* b2 = (const float*)d_in[5];
    const int* training = (const int*)d_in[6];
    float* out = (float*)d_out;

    // ws layout (all offsets 16B aligned); total ~43 MB
    char* p = (char*)d_ws;
    float* CB = (float*)p;          p += (size_t)NCB * DK * 4;       // 3,670,016
    _Float16* xh = (_Float16*)p;    p += (size_t)N_ROWS * DK * 2;    // 33,554,432
    _Float16* cbh = (_Float16*)p;   p += (size_t)NCB * DK * 2;       // 1,835,008
    uint2* candbuf = (uint2*)p;     p += (size_t)N_ROWS * NTILE * 8; // 3,670,016
    float* norms = (float*)p;       p += NCB * 4;                    // 7,168
    float2* lossPart = (float2*)p;  p += (size_t)NBLK_RG * 8;        // 65,536
    int* used = (int*)p;            p += 4096;

    build_subcb<<<dim3(8, 112), dim3(256), 0, stream>>>(c, W1, b1, W2, b2, CB, cbh);
    row_norms<<<dim3(NCB), dim3(64), 0, stream>>>(CB, norms);
    cvt_x<<<dim3(8192), dim3(256), 0, stream>>>(x, xh, used);
    gemm_topk<<<dim3(3584), dim3(64), 0, stream>>>(xh, cbh, norms, candbuf);
    rescue_gather<<<dim3(NBLK_RG), dim3(256), 0, stream>>>(
        x, CB, norms, candbuf, out + MAIN_OFF, out + SUB_OFF, lossPart, used);
    finalize_kernel<<<dim3(1), dim3(256), 0, stream>>>(used, lossPart, training, out);
}

// Round 7
// 408.852 us; speedup vs baseline: 1.0489x; 1.0489x over previous
//
#include <hip/hip_runtime.h>
#include <cstdint>

typedef unsigned short ushort_t;
typedef unsigned int uint_t;
typedef _Float16 f16x8 __attribute__((ext_vector_type(8)));
typedef float f32x4 __attribute__((ext_vector_type(4)));
typedef uint_t u32x2 __attribute__((ext_vector_type(2)));

#define N_ROWS 32768
#define DK 512
#define NC_MAIN 1024
#define NCB 1792  // 1024 + 512 + 256
#define NTILE 14  // 1792 / 128
#define NBLK_RG 4096  // rescue_gather blocks (8 rows each)

// d_out layout (floats, concatenated reference outputs)
#define MAIN_OFF 0
#define SUB_OFF  16777216
#define LOSS_OFF 33554432
#define MSK_OFF  33554433
#define UNIQ_OFF 33562625

__device__ __forceinline__ uint_t umin_(uint_t a, uint_t b) { return a < b ? a : b; }
__device__ __forceinline__ uint_t umax_(uint_t a, uint_t b) { return a > b ? a : b; }

// Non-temporal helpers (streamed-once data: skip L2 retention)
__device__ __forceinline__ float4 ntld4(const float4* p) {
    f32x4 v = __builtin_nontemporal_load((const f32x4*)p);
    return make_float4(v[0], v[1], v[2], v[3]);
}
__device__ __forceinline__ void ntst4(float4* p, float4 v) {
    f32x4 t; t[0] = v.x; t[1] = v.y; t[2] = v.z; t[3] = v.w;
    __builtin_nontemporal_store(t, (f32x4*)p);
}
__device__ __forceinline__ uint2 ntld2(const uint2* p) {
    u32x2 v = __builtin_nontemporal_load((const u32x2*)p);
    return make_uint2(v[0], v[1]);
}

// ---------------------------------------------------------------------------
// Fused prep: [0,896) build CB+cbh; [896,9088) x->f16 (+ zero `used` and out
// msk region). NOTE: row_norms is NOT fused here — it reads CB written by
// the build blocks and inter-block ordering within one launch is undefined
// (round-5 post-mortem: that race corrupted norms -> unique_rows off by 144).
// The two phases here are fully independent: build reads c/W1/b1/W2/b2 and
// writes CB/cbh; cvt reads x and writes xh/used/msk.
__global__ __launch_bounds__(256) void prep_kernel(
    const float* __restrict__ c, const float* __restrict__ W1,
    const float* __restrict__ b1, const float* __restrict__ W2,
    const float* __restrict__ b2, float* __restrict__ CB,
    _Float16* __restrict__ cbh,
    const float* __restrict__ x, _Float16* __restrict__ xh,
    int* __restrict__ used, float* __restrict__ out)
{
    const int bid = blockIdx.x;
    const int tid = threadIdx.x;
    if (bid < 896) {
        // ---- build_subcb: 8 col-blocks x 112 row-blocks ----
        int tx = tid & 63, ty = tid >> 6;
        int col = (bid & 7) * 64 + tx;
        int row0 = (bid >> 3) * 16 + ty * 4;
        if (row0 < 1024) {
#pragma unroll
            for (int r = 0; r < 4; ++r) {
                float v = c[(row0 + r) * DK + col];
                CB[(row0 + r) * DK + col] = v;
                cbh[(row0 + r) * DK + col] = (_Float16)v;
            }
        } else {
            int i0 = row0 - 1024;
            const float* W;
            const float* b;
            if (i0 < 512) { W = W1; b = b1; }
            else          { W = W2; b = b2; i0 -= 512; }
            float acc[4] = {0.f, 0.f, 0.f, 0.f};
#pragma unroll 8
            for (int j = 0; j < 1024; ++j) {
                float cv = c[j * DK + col];
#pragma unroll
                for (int r = 0; r < 4; ++r)
                    acc[r] += W[(i0 + r) * 1024 + j] * cv;
            }
#pragma unroll
            for (int r = 0; r < 4; ++r) {
                float v = acc[r] + b[i0 + r];
                CB[(row0 + r) * DK + col] = v;
                cbh[(row0 + r) * DK + col] = (_Float16)v;
            }
        }
    } else {
        // ---- cvt_x: fp32 -> f16, 8 elems/thread; init used + msk ----
        int i = (bid - 896) * 256 + tid;
        if (i < 1024) used[i] = 0;
        if (i < 8192) out[MSK_OFF + i] = 0.f;
        const float4* p = (const float4*)x + (size_t)i * 2;
        float4 a = p[0], b = p[1];
        f16x8 o;
        o[0] = (_Float16)a.x; o[1] = (_Float16)a.y; o[2] = (_Float16)a.z; o[3] = (_Float16)a.w;
        o[4] = (_Float16)b.x; o[5] = (_Float16)b.y; o[6] = (_Float16)b.z; o[7] = (_Float16)b.w;
        *((f16x8*)xh + i) = o;
    }
}

// ---------------------------------------------------------------------------
// Separate dispatch: needs CB fully written (ordered after prep_kernel).
__global__ __launch_bounds__(64) void row_norms(const float* __restrict__ CB,
                                                float* __restrict__ norms) {
    int row = blockIdx.x;
    int lane = threadIdx.x;
    const float4* p = (const float4*)(CB + (size_t)row * DK);
    float s = 0.f;
#pragma unroll
    for (int i = lane; i < 128; i += 64) {
        float4 v = p[i];
        s += v.x * v.x + v.y * v.y + v.z * v.z + v.w * v.w;
    }
#pragma unroll
    for (int off = 32; off; off >>= 1) s += __shfl_down(s, off, 64);
    if (lane == 0) norms[row] = s;
}

// ---------------------------------------------------------------------------
__device__ __forceinline__ void async16(void* lds, const void* g) {
    __builtin_amdgcn_global_load_lds(
        (const __attribute__((address_space(1))) unsigned int*)(uintptr_t)g,
        (__attribute__((address_space(3))) unsigned int*)(uintptr_t)lds,
        16, 0, 0);
}

// ---------------------------------------------------------------------------
// MFMA f16 GEMM S = xh . cbh^T with per-(row, 128-col-tile) top-2 epilogue.
// Proven baseline structure (94.4 us, MfmaUtil ~26%): 256 thr = 4 waves
// (2x2), tile 128x128, BK=32, double-buffered LDS, one __syncthreads/K-iter.
// Rounds 1-4 established that bank conflicts, barrier count, and per-wave
// LDS traffic do NOT move this kernel (latency-limited at ~640 TF for this
// L3-resident K=512 shape); kept in verified form.
__global__ __launch_bounds__(256) void gemm_topk(
    const _Float16* __restrict__ xh, const _Float16* __restrict__ cbh,
    const float* __restrict__ norms, uint2* __restrict__ candbuf)
{
    __shared__ __align__(16) ushort_t As[2][128 * 32];
    __shared__ __align__(16) ushort_t Bs[2][128 * 32];
    __shared__ uint2 cand[128][2];

    const int tid = threadIdx.x;
    const int lane = tid & 63;
    const int wid = tid >> 6;
    const int wy = wid >> 1, wx = wid & 1;
    const int lane15 = lane & 15, q = lane >> 4;

    // XCD-aware remap (launch order: blockIdx.x fastest)
    const int bid = blockIdx.y * NTILE + blockIdx.x;
    const int xcd = bid & 7;
    const int slot = bid >> 3;             // 0..447
    const int tileN = slot % NTILE;        // 0..13
    const int rowG = slot / NTILE;         // 0..31
    const int rowBase = (rowG * 8 + xcd) * 128;
    const int c0 = tileN * 128;

    // staging offsets: 512 granules (16B) per matrix per buffer, 2/thread
    size_t aoff[2], boff[2];
    int ldsoff[2];
#pragma unroll
    for (int i = 0; i < 2; ++i) {
        int gid = i * 256 + tid;     // 0..511
        int row = gid >> 2;          // 0..127
        int gp = gid & 3;
        int gsw = gp ^ (row & 3);
        aoff[i] = (size_t)(rowBase + row) * DK + gsw * 8;
        boff[i] = (size_t)(c0 + row) * DK + gsw * 8;
        ldsoff[i] = gid * 8;         // f16 elements
    }

    // fragment LDS row bases
    int rA[4], rB[4];
#pragma unroll
    for (int t = 0; t < 4; ++t) {
        rA[t] = wy * 64 + t * 16 + lane15;
        rB[t] = wx * 64 + t * 16 + lane15;
    }

    f32x4 acc[4][4];
#pragma unroll
    for (int mr = 0; mr < 4; ++mr)
#pragma unroll
        for (int nc = 0; nc < 4; ++nc) acc[mr][nc] = (f32x4)0.f;

    // preload chunk 0 into buffer 0
#pragma unroll
    for (int i = 0; i < 2; ++i) {
        async16(&As[0][ldsoff[i]], xh + aoff[i]);
        async16(&Bs[0][ldsoff[i]], cbh + boff[i]);
    }

#pragma unroll
    for (int it = 0; it < 16; ++it) {
        const int cur = it & 1;
        __syncthreads();   // drains this iter's loads; all waves done with other buf
        if (it < 15) {
            const int nxt = cur ^ 1;
            const int kk = (it + 1) * 32;
#pragma unroll
            for (int i = 0; i < 2; ++i) {
                async16(&As[nxt][ldsoff[i]], xh + aoff[i] + kk);
                async16(&Bs[nxt][ldsoff[i]], cbh + boff[i] + kk);
            }
        }
        f16x8 av[4], bv[4];
#pragma unroll
        for (int mr = 0; mr < 4; ++mr)
            av[mr] = *(const f16x8*)&As[cur][rA[mr] * 32 + (q ^ (rA[mr] & 3)) * 8];
#pragma unroll
        for (int nc = 0; nc < 4; ++nc)
            bv[nc] = *(const f16x8*)&Bs[cur][rB[nc] * 32 + (q ^ (rB[nc] & 3)) * 8];
#pragma unroll
        for (int mr = 0; mr < 4; ++mr)
#pragma unroll
            for (int nc = 0; nc < 4; ++nc)
                acc[mr][nc] = __builtin_amdgcn_mfma_f32_16x16x32_f16(
                    av[mr], bv[nc], acc[mr][nc], 0, 0, 0);
    }

    // ---------------- epilogue: per-row top-2 over the 128-col tile ----------
    float nrm[4];
    uint_t colGlob[4];
#pragma unroll
    for (int nc = 0; nc < 4; ++nc) {
        colGlob[nc] = (uint_t)(c0 + wx * 64 + nc * 16 + lane15);
        nrm[nc] = norms[colGlob[nc]];
    }

#pragma unroll
    for (int mr = 0; mr < 4; ++mr) {
#pragma unroll
        for (int r = 0; r < 4; ++r) {
            uint_t k[4];
#pragma unroll
            for (int nc = 0; nc < 4; ++nc) {
                float s = fmaf(-2.f, acc[mr][nc][r], nrm[nc]);
                uint_t b = __float_as_uint(s);
                uint_t u = b ^ ((uint_t)((int)b >> 31) | 0x80000000u);
                k[nc] = (u & 0xFFFFF800u) | colGlob[nc];
            }
            uint_t lo01 = umin_(k[0], k[1]), hi01 = umax_(k[0], k[1]);
            uint_t lo23 = umin_(k[2], k[3]), hi23 = umax_(k[2], k[3]);
            uint_t k1 = umin_(lo01, lo23);
            uint_t k2 = umin_(umin_(hi01, hi23), umax_(lo01, lo23));
#pragma unroll
            for (int m = 1; m <= 8; m <<= 1) {
                uint_t o1 = __shfl_xor(k1, m, 64);
                uint_t o2 = __shfl_xor(k2, m, 64);
                uint_t n1 = umin_(k1, o1);
                uint_t n2 = umin_(umax_(k1, o1), umin_(k2, o2));
                k1 = n1; k2 = n2;
            }
            if (lane15 == 0) {
                int rloc = wy * 64 + mr * 16 + q * 4 + r;
                cand[rloc][wx] = make_uint2(k1, k2);
            }
        }
    }
    __syncthreads();
    if (tid < 128) {
        uint2 a = cand[tid][0], b = cand[tid][1];
        uint_t k1 = umin_(a.x, b.x);
        uint_t k2 = umin_(umax_(a.x, b.x), umin_(a.y, b.y));
        candbuf[(size_t)(rowBase + tid) * NTILE + tileN] = make_uint2(k1, k2);
    }
}

// ---------------------------------------------------------------------------
// Per x-row: merge tile candidate keys per segment (top-4, pure u32 min/max on
// wave-uniform values), rescore exactly in fp32, pick argmin (tie -> lowest
// idx), gather rows, write outputs (non-temporal: never re-read), per-block
// loss partials, mark used. One wave per row; 8 rows per block.
__device__ __forceinline__ void push4u(uint_t v, uint_t* bs) {
#pragma unroll
    for (int j = 0; j < 4; ++j) {
        uint_t lo = umin_(v, bs[j]);
        uint_t hi = umax_(v, bs[j]);
        bs[j] = lo; v = hi;
    }
}

__global__ __launch_bounds__(512) void rescue_gather(
    const float* __restrict__ x, const float* __restrict__ CB,
    const float* __restrict__ norms, const uint2* __restrict__ candbuf,
    float* __restrict__ main_out, float* __restrict__ sub_out,
    float2* __restrict__ lossPart, int* __restrict__ used)
{
    const int lane = threadIdx.x & 63;
    const int wv = threadIdx.x >> 6;
    const int r = blockIdx.x * 8 + wv;

    const float4* xp = (const float4*)(x + (size_t)r * DK) + lane * 2;
    float4 xa = ntld4(xp), xb = ntld4(xp + 1);

    const uint2* cbp = candbuf + (size_t)r * NTILE;

    int si[12];
    {
        uint_t bs[4];
        // main: tiles 0..7
#pragma unroll
        for (int j = 0; j < 4; ++j) bs[j] = 0xFFFFFFFFu;
#pragma unroll
        for (int t = 0; t < 8; ++t) {
            uint2 e = ntld2(&cbp[t]);
            push4u(__builtin_amdgcn_readfirstlane(e.x), bs);
            push4u(__builtin_amdgcn_readfirstlane(e.y), bs);
        }
#pragma unroll
        for (int j = 0; j < 4; ++j) si[j] = (int)(bs[j] & 2047u);
        // s1: tiles 8..11
#pragma unroll
        for (int j = 0; j < 4; ++j) bs[j] = 0xFFFFFFFFu;
#pragma unroll
        for (int t = 8; t < 12; ++t) {
            uint2 e = ntld2(&cbp[t]);
            push4u(__builtin_amdgcn_readfirstlane(e.x), bs);
            push4u(__builtin_amdgcn_readfirstlane(e.y), bs);
        }
#pragma unroll
        for (int j = 0; j < 4; ++j) si[4 + j] = (int)(bs[j] & 2047u);
        // s2: tiles 12..13 (exactly 4 candidates)
#pragma unroll
        for (int j = 0; j < 4; ++j) bs[j] = 0xFFFFFFFFu;
#pragma unroll
        for (int t = 12; t < 14; ++t) {
            uint2 e = ntld2(&cbp[t]);
            push4u(__builtin_amdgcn_readfirstlane(e.x), bs);
            push4u(__builtin_amdgcn_readfirstlane(e.y), bs);
        }
#pragma unroll
        for (int j = 0; j < 4; ++j) si[8 + j] = (int)(bs[j] & 2047u);
    }

    // exact fp32 dots for all 12 candidates (CB stays cached: small + reused)
    float d[12];
#pragma unroll
    for (int k = 0; k < 12; ++k) {
        const float4* cp = (const float4*)(CB + (size_t)si[k] * DK) + lane * 2;
        float4 a = cp[0], b = cp[1];
        d[k] = xa.x * a.x + xa.y * a.y + xa.z * a.z + xa.w * a.w
             + xb.x * b.x + xb.y * b.y + xb.z * b.z + xb.w * b.w;
    }
#pragma unroll
    for (int off = 32; off; off >>= 1)
#pragma unroll
        for (int k = 0; k < 12; ++k) d[k] += __shfl_xor(d[k], off, 64);

    float sc[12];
#pragma unroll
    for (int k = 0; k < 12; ++k) sc[k] = norms[si[k]] - 2.f * d[k];

    int pick[3];
#pragma unroll
    for (int g = 0; g < 3; ++g) {
        float bv = sc[g * 4]; int bidx = si[g * 4];
#pragma unroll
        for (int k = 1; k < 4; ++k) {
            float v = sc[g * 4 + k]; int idx = si[g * 4 + k];
            if (v < bv || (v == bv && idx < bidx)) { bv = v; bidx = idx; }
        }
        pick[g] = bidx;
    }
    const int A = pick[0], B = pick[1], C = pick[2];

    // gather + write + loss
    const float4* pa = (const float4*)(CB + (size_t)A * DK) + lane * 2;
    const float4* pb = (const float4*)(CB + (size_t)B * DK) + lane * 2;
    const float4* pc = (const float4*)(CB + (size_t)C * DK) + lane * 2;
    float4* mo = (float4*)(main_out + (size_t)r * DK) + lane * 2;
    float4* so = (float4*)(sub_out + (size_t)r * DK) + lane * 2;
    float em = 0.f, es = 0.f;
#pragma unroll
    for (int i = 0; i < 2; ++i) {
        float4 xq = (i == 0) ? xa : xb;
        float4 cm = pa[i];
        float4 q1 = pb[i];
        float4 q2 = pc[i];
        float4 cs;
        cs.x = 0.5f * (q1.x + q2.x);
        cs.y = 0.5f * (q1.y + q2.y);
        cs.z = 0.5f * (q1.z + q2.z);
        cs.w = 0.5f * (q1.w + q2.w);
        ntst4(&mo[i], cm);
        ntst4(&so[i], cs);
        float t;
        t = cm.x - xq.x; em += t * t;
        t = cm.y - xq.y; em += t * t;
        t = cm.z - xq.z; em += t * t;
        t = cm.w - xq.w; em += t * t;
        t = cs.x - xq.x; es += t * t;
        t = cs.y - xq.y; es += t * t;
        t = cs.z - xq.z; es += t * t;
        t = cs.w - xq.w; es += t * t;
    }
#pragma unroll
    for (int off = 32; off; off >>= 1) {
        em += __shfl_down(em, off, 64);
        es += __shfl_down(es, off, 64);
    }
    __shared__ float sm[16];
    if (lane == 0) {
        sm[wv] = em; sm[8 + wv] = es;
        used[A] = 1;  // benign race: same value
    }
    __syncthreads();
    if (threadIdx.x == 0) {
        float e0 = 0.f, e1 = 0.f;
#pragma unroll
        for (int i = 0; i < 8; ++i) { e0 += sm[i]; e1 += sm[8 + i]; }
        lossPart[blockIdx.x] = make_float2(e0, e1);
    }
}

// ---------------------------------------------------------------------------
// Reduce 4096 loss partials + count used codes + write scalars.
__global__ __launch_bounds__(256) void finalize_kernel(
    const int* __restrict__ used, const float2* __restrict__ lossPart,
    const int* __restrict__ training, float* __restrict__ out)
{
    int tid = threadIdx.x;
    int cnt = 0;
    for (int i = tid; i < 1024; i += 256) cnt += (used[i] != 0);
    float em = 0.f, es = 0.f;
    for (int i = tid; i < NBLK_RG; i += 256) {
        float2 p = lossPart[i];
        em += p.x; es += p.y;
    }
#pragma unroll
    for (int off = 32; off; off >>= 1) {
        cnt += __shfl_down(cnt, off, 64);
        em += __shfl_down(em, off, 64);
        es += __shfl_down(es, off, 64);
    }
    __shared__ int sc[4];
    __shared__ float se[4], ss[4];
    if ((tid & 63) == 0) { sc[tid >> 6] = cnt; se[tid >> 6] = em; ss[tid >> 6] = es; }
    __syncthreads();
    if (tid == 0) {
        int total = sc[0] + sc[1] + sc[2] + sc[3];
        float tl = 0.f;
        if (*training) {
            float l0 = se[0] + se[1] + se[2] + se[3];
            float l1 = ss[0] + ss[1] + ss[2] + ss[3];
            tl = 1.25f * (l0 + l1) * (1.0f / ((float)N_ROWS * (float)DK));
        }
        out[LOSS_OFF] = tl;
        out[UNIQ_OFF] = (float)total;
    }
}

// ---------------------------------------------------------------------------
extern "C" void kernel_launch(void* const* d_in, const int* in_sizes, int n_in,
                              void* d_out, int out_size, void* d_ws, size_t ws_size,
                              hipStream_t stream) {
    const float* x = (const float*)d_in[0];
    const float* c = (const float*)d_in[1];
    const float* W1 = (const float*)d_in[2];
    const float* b1 = (const float*)d_in[3];
    const float* W2 = (const float*)d_in[4];
    const float* b2 = (const float*)d_in[5];
    const int* training = (const int*)d_in[6];
    float* out = (float*)d_out;

    // ws layout (all offsets 16B aligned); total ~43 MB
    char* p = (char*)d_ws;
    float* CB = (float*)p;          p += (size_t)NCB * DK * 4;       // 3,670,016
    _Float16* xh = (_Float16*)p;    p += (size_t)N_ROWS * DK * 2;    // 33,554,432
    _Float16* cbh = (_Float16*)p;   p += (size_t)NCB * DK * 2;       // 1,835,008
    uint2* candbuf = (uint2*)p;     p += (size_t)N_ROWS * NTILE * 8; // 3,670,016
    float* norms = (float*)p;       p += NCB * 4;                    // 7,168
    float2* lossPart = (float2*)p;  p += (size_t)NBLK_RG * 8;        // 32,768
    int* used = (int*)p;            p += 4096;

    prep_kernel<<<dim3(9088), dim3(256), 0, stream>>>(
        c, W1, b1, W2, b2, CB, cbh, x, xh, used, out);
    row_norms<<<dim3(NCB), dim3(64), 0, stream>>>(CB, norms);
    gemm_topk<<<dim3(NTILE, 256), dim3(256), 0, stream>>>(xh, cbh, norms, candbuf);
    rescue_gather<<<dim3(NBLK_RG), dim3(512), 0, stream>>>(
        x, CB, norms, candbuf, out + MAIN_OFF, out + SUB_OFF, lossPart, used);
    finalize_kernel<<<dim3(1), dim3(256), 0, stream>>>(used, lossPart, training, out);
}

// Round 8
// 362.495 us; speedup vs baseline: 1.1830x; 1.1279x over previous
//
#include <hip/hip_runtime.h>
#include <cstdint>

typedef unsigned short ushort_t;
typedef unsigned int uint_t;
typedef _Float16 f16x8 __attribute__((ext_vector_type(8)));
typedef float f32x4 __attribute__((ext_vector_type(4)));
typedef uint_t u32x2 __attribute__((ext_vector_type(2)));

#define N_ROWS 32768
#define DK 512
#define NC_MAIN 1024
#define NCB 1792  // 1024 + 512 + 256
#define NTILE 14  // 1792 / 128
#define NBLK_RG 4096  // rescue_gather blocks (8 rows each)

// d_out layout (floats, concatenated reference outputs)
#define MAIN_OFF 0
#define SUB_OFF  16777216
#define LOSS_OFF 33554432
#define MSK_OFF  33554433
#define UNIQ_OFF 33562625

__device__ __forceinline__ uint_t umin_(uint_t a, uint_t b) { return a < b ? a : b; }
__device__ __forceinline__ uint_t umax_(uint_t a, uint_t b) { return a > b ? a : b; }

// Non-temporal helpers (streamed-once data: skip L2 retention)
__device__ __forceinline__ float4 ntld4(const float4* p) {
    f32x4 v = __builtin_nontemporal_load((const f32x4*)p);
    return make_float4(v[0], v[1], v[2], v[3]);
}
__device__ __forceinline__ void ntst4(float4* p, float4 v) {
    f32x4 t; t[0] = v.x; t[1] = v.y; t[2] = v.z; t[3] = v.w;
    __builtin_nontemporal_store(t, (f32x4*)p);
}
__device__ __forceinline__ uint2 ntld2(const uint2* p) {
    u32x2 v = __builtin_nontemporal_load((const u32x2*)p);
    return make_uint2(v[0], v[1]);
}

// ---------------------------------------------------------------------------
// Fused prep: [0,896) build CB+cbh; [896,9088) x->f16 (+ zero `used` and out
// msk region). row_norms stays a separate dispatch (reads CB; inter-block
// ordering within one launch is undefined — round-5 race).
//
// Round-7 profile: prep = 95 us at 913 GB/s, VALUBusy 19%, nothing saturated
// -> latency-bound. Culprit: W@c blocks' per-thread 2KB-strided c loads
// (1024 deps x ~200-900 cyc). Fix: LDS-tile the matmul — stage c-chunk
// (128x64 f32, 32KB) + W-chunk (16x128, 8KB) cooperatively, inner loop is
// conflict-free ds_read_b32 + wave-uniform broadcast + FMA.
__global__ __launch_bounds__(256) void prep_kernel(
    const float* __restrict__ c, const float* __restrict__ W1,
    const float* __restrict__ b1, const float* __restrict__ W2,
    const float* __restrict__ b2, float* __restrict__ CB,
    _Float16* __restrict__ cbh,
    const float* __restrict__ x, _Float16* __restrict__ xh,
    int* __restrict__ used, float* __restrict__ out)
{
    __shared__ __align__(16) float c_s[128][64];   // 32 KiB  [j][col]
    __shared__ __align__(16) float w_s[16][128];   //  8 KiB  [row][j]

    const int bid = blockIdx.x;
    const int tid = threadIdx.x;
    if (bid < 896) {
        // ---- build_subcb: 8 col-blocks x 112 row-blocks (16 rows each) ----
        const int tx = tid & 63, ty = tid >> 6;
        const int col0 = (bid & 7) * 64;
        const int base = (bid >> 3) * 16;       // CB row base (multiple of 16)
        const int col = col0 + tx;
        if (base < 1024) {
            // plain copy of c
#pragma unroll
            for (int r = 0; r < 4; ++r) {
                float v = c[(base + ty * 4 + r) * DK + col];
                CB[(base + ty * 4 + r) * DK + col] = v;
                cbh[(base + ty * 4 + r) * DK + col] = (_Float16)v;
            }
        } else {
            const float* W;
            const float* b;
            int wbase;
            if (base < 1536) { W = W1; b = b1; wbase = base - 1024; }
            else             { W = W2; b = b2; wbase = base - 1536; }
            float acc[4] = {0.f, 0.f, 0.f, 0.f};
#pragma unroll 1
            for (int ch = 0; ch < 8; ++ch) {
                const int j0 = ch * 128;
                // stage c[j0:j0+128][col0:col0+64] -> c_s (2048 float4s)
#pragma unroll
                for (int k = 0; k < 8; ++k) {
                    int g = k * 256 + tid;
                    int row = g >> 4, gr = g & 15;
                    *(float4*)&c_s[row][gr * 4] =
                        *(const float4*)&c[(size_t)(j0 + row) * DK + col0 + gr * 4];
                }
                // stage W[wbase:wbase+16][j0:j0+128] -> w_s (512 float4s)
#pragma unroll
                for (int k = 0; k < 2; ++k) {
                    int g = k * 256 + tid;
                    int rw = g >> 5, gr = g & 31;
                    *(float4*)&w_s[rw][gr * 4] =
                        *(const float4*)&W[(size_t)(wbase + rw) * 1024 + j0 + gr * 4];
                }
                __syncthreads();
                // c_s[j][tx]: 64 lanes consecutive floats -> 2 lanes/bank, free.
                // w_s[row][j]: wave-uniform -> broadcast, free.
#pragma unroll 8
                for (int j = 0; j < 128; ++j) {
                    float cv = c_s[j][tx];
#pragma unroll
                    for (int r = 0; r < 4; ++r)
                        acc[r] += w_s[ty * 4 + r][j] * cv;
                }
                __syncthreads();
            }
#pragma unroll
            for (int r = 0; r < 4; ++r) {
                float v = acc[r] + b[wbase + ty * 4 + r];
                CB[(size_t)(base + ty * 4 + r) * DK + col] = v;
                cbh[(size_t)(base + ty * 4 + r) * DK + col] = (_Float16)v;
            }
        }
    } else {
        // ---- cvt_x: fp32 -> f16, 8 elems/thread; init used + msk ----
        int i = (bid - 896) * 256 + tid;
        if (i < 1024) used[i] = 0;
        if (i < 8192) out[MSK_OFF + i] = 0.f;
        const float4* p = (const float4*)x + (size_t)i * 2;
        float4 a = p[0], b = p[1];
        f16x8 o;
        o[0] = (_Float16)a.x; o[1] = (_Float16)a.y; o[2] = (_Float16)a.z; o[3] = (_Float16)a.w;
        o[4] = (_Float16)b.x; o[5] = (_Float16)b.y; o[6] = (_Float16)b.z; o[7] = (_Float16)b.w;
        *((f16x8*)xh + i) = o;
    }
}

// ---------------------------------------------------------------------------
// Separate dispatch: needs CB fully written (ordered after prep_kernel).
__global__ __launch_bounds__(64) void row_norms(const float* __restrict__ CB,
                                                float* __restrict__ norms) {
    int row = blockIdx.x;
    int lane = threadIdx.x;
    const float4* p = (const float4*)(CB + (size_t)row * DK);
    float s = 0.f;
#pragma unroll
    for (int i = lane; i < 128; i += 64) {
        float4 v = p[i];
        s += v.x * v.x + v.y * v.y + v.z * v.z + v.w * v.w;
    }
#pragma unroll
    for (int off = 32; off; off >>= 1) s += __shfl_down(s, off, 64);
    if (lane == 0) norms[row] = s;
}

// ---------------------------------------------------------------------------
__device__ __forceinline__ void async16(void* lds, const void* g) {
    __builtin_amdgcn_global_load_lds(
        (const __attribute__((address_space(1))) unsigned int*)(uintptr_t)g,
        (__attribute__((address_space(3))) unsigned int*)(uintptr_t)lds,
        16, 0, 0);
}

// ---------------------------------------------------------------------------
// MFMA f16 GEMM S = xh . cbh^T with per-(row, 128-col-tile) top-2 epilogue.
// Proven baseline structure (94.4 us, MfmaUtil ~26%): 256 thr = 4 waves
// (2x2), tile 128x128, BK=32, double-buffered LDS, one __syncthreads/K-iter.
// Rounds 1-4 established that bank conflicts, barrier count, and per-wave
// LDS traffic do NOT move this kernel (latency-limited at ~640 TF for this
// L3-resident K=512 shape); kept in verified form.
__global__ __launch_bounds__(256) void gemm_topk(
    const _Float16* __restrict__ xh, const _Float16* __restrict__ cbh,
    const float* __restrict__ norms, uint2* __restrict__ candbuf)
{
    __shared__ __align__(16) ushort_t As[2][128 * 32];
    __shared__ __align__(16) ushort_t Bs[2][128 * 32];
    __shared__ uint2 cand[128][2];

    const int tid = threadIdx.x;
    const int lane = tid & 63;
    const int wid = tid >> 6;
    const int wy = wid >> 1, wx = wid & 1;
    const int lane15 = lane & 15, q = lane >> 4;

    // XCD-aware remap (launch order: blockIdx.x fastest)
    const int bid = blockIdx.y * NTILE + blockIdx.x;
    const int xcd = bid & 7;
    const int slot = bid >> 3;             // 0..447
    const int tileN = slot % NTILE;        // 0..13
    const int rowG = slot / NTILE;         // 0..31
    const int rowBase = (rowG * 8 + xcd) * 128;
    const int c0 = tileN * 128;

    // staging offsets: 512 granules (16B) per matrix per buffer, 2/thread
    size_t aoff[2], boff[2];
    int ldsoff[2];
#pragma unroll
    for (int i = 0; i < 2; ++i) {
        int gid = i * 256 + tid;     // 0..511
        int row = gid >> 2;          // 0..127
        int gp = gid & 3;
        int gsw = gp ^ (row & 3);
        aoff[i] = (size_t)(rowBase + row) * DK + gsw * 8;
        boff[i] = (size_t)(c0 + row) * DK + gsw * 8;
        ldsoff[i] = gid * 8;         // f16 elements
    }

    // fragment LDS row bases
    int rA[4], rB[4];
#pragma unroll
    for (int t = 0; t < 4; ++t) {
        rA[t] = wy * 64 + t * 16 + lane15;
        rB[t] = wx * 64 + t * 16 + lane15;
    }

    f32x4 acc[4][4];
#pragma unroll
    for (int mr = 0; mr < 4; ++mr)
#pragma unroll
        for (int nc = 0; nc < 4; ++nc) acc[mr][nc] = (f32x4)0.f;

    // preload chunk 0 into buffer 0
#pragma unroll
    for (int i = 0; i < 2; ++i) {
        async16(&As[0][ldsoff[i]], xh + aoff[i]);
        async16(&Bs[0][ldsoff[i]], cbh + boff[i]);
    }

#pragma unroll
    for (int it = 0; it < 16; ++it) {
        const int cur = it & 1;
        __syncthreads();   // drains this iter's loads; all waves done with other buf
        if (it < 15) {
            const int nxt = cur ^ 1;
            const int kk = (it + 1) * 32;
#pragma unroll
            for (int i = 0; i < 2; ++i) {
                async16(&As[nxt][ldsoff[i]], xh + aoff[i] + kk);
                async16(&Bs[nxt][ldsoff[i]], cbh + boff[i] + kk);
            }
        }
        f16x8 av[4], bv[4];
#pragma unroll
        for (int mr = 0; mr < 4; ++mr)
            av[mr] = *(const f16x8*)&As[cur][rA[mr] * 32 + (q ^ (rA[mr] & 3)) * 8];
#pragma unroll
        for (int nc = 0; nc < 4; ++nc)
            bv[nc] = *(const f16x8*)&Bs[cur][rB[nc] * 32 + (q ^ (rB[nc] & 3)) * 8];
#pragma unroll
        for (int mr = 0; mr < 4; ++mr)
#pragma unroll
            for (int nc = 0; nc < 4; ++nc)
                acc[mr][nc] = __builtin_amdgcn_mfma_f32_16x16x32_f16(
                    av[mr], bv[nc], acc[mr][nc], 0, 0, 0);
    }

    // ---------------- epilogue: per-row top-2 over the 128-col tile ----------
    float nrm[4];
    uint_t colGlob[4];
#pragma unroll
    for (int nc = 0; nc < 4; ++nc) {
        colGlob[nc] = (uint_t)(c0 + wx * 64 + nc * 16 + lane15);
        nrm[nc] = norms[colGlob[nc]];
    }

#pragma unroll
    for (int mr = 0; mr < 4; ++mr) {
#pragma unroll
        for (int r = 0; r < 4; ++r) {
            uint_t k[4];
#pragma unroll
            for (int nc = 0; nc < 4; ++nc) {
                float s = fmaf(-2.f, acc[mr][nc][r], nrm[nc]);
                uint_t b = __float_as_uint(s);
                uint_t u = b ^ ((uint_t)((int)b >> 31) | 0x80000000u);
                k[nc] = (u & 0xFFFFF800u) | colGlob[nc];
            }
            uint_t lo01 = umin_(k[0], k[1]), hi01 = umax_(k[0], k[1]);
            uint_t lo23 = umin_(k[2], k[3]), hi23 = umax_(k[2], k[3]);
            uint_t k1 = umin_(lo01, lo23);
            uint_t k2 = umin_(umin_(hi01, hi23), umax_(lo01, lo23));
#pragma unroll
            for (int m = 1; m <= 8; m <<= 1) {
                uint_t o1 = __shfl_xor(k1, m, 64);
                uint_t o2 = __shfl_xor(k2, m, 64);
                uint_t n1 = umin_(k1, o1);
                uint_t n2 = umin_(umax_(k1, o1), umin_(k2, o2));
                k1 = n1; k2 = n2;
            }
            if (lane15 == 0) {
                int rloc = wy * 64 + mr * 16 + q * 4 + r;
                cand[rloc][wx] = make_uint2(k1, k2);
            }
        }
    }
    __syncthreads();
    if (tid < 128) {
        uint2 a = cand[tid][0], b = cand[tid][1];
        uint_t k1 = umin_(a.x, b.x);
        uint_t k2 = umin_(umax_(a.x, b.x), umin_(a.y, b.y));
        candbuf[(size_t)(rowBase + tid) * NTILE + tileN] = make_uint2(k1, k2);
    }
}

// ---------------------------------------------------------------------------
// Per x-row: merge tile candidate keys per segment (top-4, pure u32 min/max on
// wave-uniform values), rescore exactly in fp32, pick argmin (tie -> lowest
// idx), gather rows, write outputs (non-temporal: never re-read), per-block
// loss partials, mark used. One wave per row; 8 rows per block.
__device__ __forceinline__ void push4u(uint_t v, uint_t* bs) {
#pragma unroll
    for (int j = 0; j < 4; ++j) {
        uint_t lo = umin_(v, bs[j]);
        uint_t hi = umax_(v, bs[j]);
        bs[j] = lo; v = hi;
    }
}

__global__ __launch_bounds__(512) void rescue_gather(
    const float* __restrict__ x, const float* __restrict__ CB,
    const float* __restrict__ norms, const uint2* __restrict__ candbuf,
    float* __restrict__ main_out, float* __restrict__ sub_out,
    float2* __restrict__ lossPart, int* __restrict__ used)
{
    const int lane = threadIdx.x & 63;
    const int wv = threadIdx.x >> 6;
    const int r = blockIdx.x * 8 + wv;

    const float4* xp = (const float4*)(x + (size_t)r * DK) + lane * 2;
    float4 xa = ntld4(xp), xb = ntld4(xp + 1);

    const uint2* cbp = candbuf + (size_t)r * NTILE;

    int si[12];
    {
        uint_t bs[4];
        // main: tiles 0..7
#pragma unroll
        for (int j = 0; j < 4; ++j) bs[j] = 0xFFFFFFFFu;
#pragma unroll
        for (int t = 0; t < 8; ++t) {
            uint2 e = ntld2(&cbp[t]);
            push4u(__builtin_amdgcn_readfirstlane(e.x), bs);
            push4u(__builtin_amdgcn_readfirstlane(e.y), bs);
        }
#pragma unroll
        for (int j = 0; j < 4; ++j) si[j] = (int)(bs[j] & 2047u);
        // s1: tiles 8..11
#pragma unroll
        for (int j = 0; j < 4; ++j) bs[j] = 0xFFFFFFFFu;
#pragma unroll
        for (int t = 8; t < 12; ++t) {
            uint2 e = ntld2(&cbp[t]);
            push4u(__builtin_amdgcn_readfirstlane(e.x), bs);
            push4u(__builtin_amdgcn_readfirstlane(e.y), bs);
        }
#pragma unroll
        for (int j = 0; j < 4; ++j) si[4 + j] = (int)(bs[j] & 2047u);
        // s2: tiles 12..13 (exactly 4 candidates)
#pragma unroll
        for (int j = 0; j < 4; ++j) bs[j] = 0xFFFFFFFFu;
#pragma unroll
        for (int t = 12; t < 14; ++t) {
            uint2 e = ntld2(&cbp[t]);
            push4u(__builtin_amdgcn_readfirstlane(e.x), bs);
            push4u(__builtin_amdgcn_readfirstlane(e.y), bs);
        }
#pragma unroll
        for (int j = 0; j < 4; ++j) si[8 + j] = (int)(bs[j] & 2047u);
    }

    // exact fp32 dots for all 12 candidates (CB stays cached: small + reused)
    float d[12];
#pragma unroll
    for (int k = 0; k < 12; ++k) {
        const float4* cp = (const float4*)(CB + (size_t)si[k] * DK) + lane * 2;
        float4 a = cp[0], b = cp[1];
        d[k] = xa.x * a.x + xa.y * a.y + xa.z * a.z + xa.w * a.w
             + xb.x * b.x + xb.y * b.y + xb.z * b.z + xb.w * b.w;
    }
#pragma unroll
    for (int off = 32; off; off >>= 1)
#pragma unroll
        for (int k = 0; k < 12; ++k) d[k] += __shfl_xor(d[k], off, 64);

    float sc[12];
#pragma unroll
    for (int k = 0; k < 12; ++k) sc[k] = norms[si[k]] - 2.f * d[k];

    int pick[3];
#pragma unroll
    for (int g = 0; g < 3; ++g) {
        float bv = sc[g * 4]; int bidx = si[g * 4];
#pragma unroll
        for (int k = 1; k < 4; ++k) {
            float v = sc[g * 4 + k]; int idx = si[g * 4 + k];
            if (v < bv || (v == bv && idx < bidx)) { bv = v; bidx = idx; }
        }
        pick[g] = bidx;
    }
    const int A = pick[0], B = pick[1], C = pick[2];

    // gather + write + loss
    const float4* pa = (const float4*)(CB + (size_t)A * DK) + lane * 2;
    const float4* pb = (const float4*)(CB + (size_t)B * DK) + lane * 2;
    const float4* pc = (const float4*)(CB + (size_t)C * DK) + lane * 2;
    float4* mo = (float4*)(main_out + (size_t)r * DK) + lane * 2;
    float4* so = (float4*)(sub_out + (size_t)r * DK) + lane * 2;
    float em = 0.f, es = 0.f;
#pragma unroll
    for (int i = 0; i < 2; ++i) {
        float4 xq = (i == 0) ? xa : xb;
        float4 cm = pa[i];
        float4 q1 = pb[i];
        float4 q2 = pc[i];
        float4 cs;
        cs.x = 0.5f * (q1.x + q2.x);
        cs.y = 0.5f * (q1.y + q2.y);
        cs.z = 0.5f * (q1.z + q2.z);
        cs.w = 0.5f * (q1.w + q2.w);
        ntst4(&mo[i], cm);
        ntst4(&so[i], cs);
        float t;
        t = cm.x - xq.x; em += t * t;
        t = cm.y - xq.y; em += t * t;
        t = cm.z - xq.z; em += t * t;
        t = cm.w - xq.w; em += t * t;
        t = cs.x - xq.x; es += t * t;
        t = cs.y - xq.y; es += t * t;
        t = cs.z - xq.z; es += t * t;
        t = cs.w - xq.w; es += t * t;
    }
#pragma unroll
    for (int off = 32; off; off >>= 1) {
        em += __shfl_down(em, off, 64);
        es += __shfl_down(es, off, 64);
    }
    __shared__ float sm[16];
    if (lane == 0) {
        sm[wv] = em; sm[8 + wv] = es;
        used[A] = 1;  // benign race: same value
    }
    __syncthreads();
    if (threadIdx.x == 0) {
        float e0 = 0.f, e1 = 0.f;
#pragma unroll
        for (int i = 0; i < 8; ++i) { e0 += sm[i]; e1 += sm[8 + i]; }
        lossPart[blockIdx.x] = make_float2(e0, e1);
    }
}

// ---------------------------------------------------------------------------
// Reduce 4096 loss partials + count used codes + write scalars.
__global__ __launch_bounds__(256) void finalize_kernel(
    const int* __restrict__ used, const float2* __restrict__ lossPart,
    const int* __restrict__ training, float* __restrict__ out)
{
    int tid = threadIdx.x;
    int cnt = 0;
    for (int i = tid; i < 1024; i += 256) cnt += (used[i] != 0);
    float em = 0.f, es = 0.f;
    for (int i = tid; i < NBLK_RG; i += 256) {
        float2 p = lossPart[i];
        em += p.x; es += p.y;
    }
#pragma unroll
    for (int off = 32; off; off >>= 1) {
        cnt += __shfl_down(cnt, off, 64);
        em += __shfl_down(em, off, 64);
        es += __shfl_down(es, off, 64);
    }
    __shared__ int sc[4];
    __shared__ float se[4], ss[4];
    if ((tid & 63) == 0) { sc[tid >> 6] = cnt; se[tid >> 6] = em; ss[tid >> 6] = es; }
    __syncthreads();
    if (tid == 0) {
        int total = sc[0] + sc[1] + sc[2] + sc[3];
        float tl = 0.f;
        if (*training) {
            float l0 = se[0] + se[1] + se[2] + se[3];
            float l1 = ss[0] + ss[1] + ss[2] + ss[3];
            tl = 1.25f * (l0 + l1) * (1.0f / ((float)N_ROWS * (float)DK));
        }
        out[LOSS_OFF] = tl;
        out[UNIQ_OFF] = (float)total;
    }
}

// ---------------------------------------------------------------------------
extern "C" void kernel_launch(void* const* d_in, const int* in_sizes, int n_in,
                              void* d_out, int out_size, void* d_ws, size_t ws_size,
                              hipStream_t stream) {
    const float* x = (const float*)d_in[0];
    const float* c = (const float*)d_in[1];
    const float* W1 = (const float*)d_in[2];
    const float* b1 = (const float*)d_in[3];
    const float* W2 = (const float*)d_in[4];
    const float* b2 = (const float*)d_in[5];
    const int* training = (const int*)d_in[6];
    float* out = (float*)d_out;

    // ws layout (all offsets 16B aligned); total ~43 MB
    char* p = (char*)d_ws;
    float* CB = (float*)p;          p += (size_t)NCB * DK * 4;       // 3,670,016
    _Float16* xh = (_Float16*)p;    p += (size_t)N_ROWS * DK * 2;    // 33,554,432
    _Float16* cbh = (_Float16*)p;   p += (size_t)NCB * DK * 2;       // 1,835,008
    uint2* candbuf = (uint2*)p;     p += (size_t)N_ROWS * NTILE * 8; // 3,670,016
    float* norms = (float*)p;       p += NCB * 4;                    // 7,168
    float2* lossPart = (float2*)p;  p += (size_t)NBLK_RG * 8;        // 32,768
    int* used = (int*)p;            p += 4096;

    prep_kernel<<<dim3(9088), dim3(256), 0, stream>>>(
        c, W1, b1, W2, b2, CB, cbh, x, xh, used, out);
    row_norms<<<dim3(NCB), dim3(64), 0, stream>>>(CB, norms);
    gemm_topk<<<dim3(NTILE, 256), dim3(256), 0, stream>>>(xh, cbh, norms, candbuf);
    rescue_gather<<<dim3(NBLK_RG), dim3(512), 0, stream>>>(
        x, CB, norms, candbuf, out + MAIN_OFF, out + SUB_OFF, lossPart, used);
    finalize_kernel<<<dim3(1), dim3(256), 0, stream>>>(used, lossPart, training, out);
}